// Round 22
// baseline (62.890 us; speedup 1.0000x reference)
//
#include <hip/hip_runtime.h>
#include <hip/hip_fp16.h>

// Sizes (fixed):
// pc1_0: [8,2048,3] -> 16384 pts   d_in[0]
// pc1_1: [8, 512,3] ->  4096 pts   d_in[1]
// pc1_3: [8, 256,1] ->  2048 vals  d_in[2]
// pc2  : [8,2048,3] -> 16384 pts   d_in[3]
// pc3  : [8, 256,3] ->  2048 pts   d_in[4]
//
// ws layout (floats):
//   [0      ,16384) minA0 : pc1_0 -> pc2   (cd, a->b)
//   [16384  ,32768) minB0 : pc2   -> pc1_0 (cd, b->a)
//   [32768  ,36864) minA1 : pc1_1 -> pc2   (seed, a->b)
//   [36864  ,53248) minB1 : pc2   -> pc1_1 (seed, b->a)
//   [53248  ,55296) minC  : pc3[b] -> pc2[b] (confidence, full f32)
//   [55296  ,55304) acc[8]
//   [55304]         ticket

#define N_MINS 55296

typedef _Float16 half8 __attribute__((ext_vector_type(8)));
typedef float f32x4 __attribute__((ext_vector_type(4)));

__device__ __forceinline__ float blockReduceSum(float v, float* sbuf) {
#pragma unroll
  for (int off = 32; off > 0; off >>= 1) v += __shfl_down(v, off, 64);
  int lane = threadIdx.x & 63;
  int wid  = threadIdx.x >> 6;
  if (lane == 0) sbuf[wid] = v;
  __syncthreads();
  float r = 0.f;
  if (threadIdx.x == 0) r = sbuf[0] + sbuf[1] + sbuf[2] + sbuf[3];
  return r;
}

// MFMA NN-min kernel on the SMALL shape (16x16x32): C/D = 4 regs (vs 16 for
// 32x32) -> ~80 live VGPR -> 4-6 waves/SIMD occupancy, the fix for the
// latency-bound signature of R13-R21 (MfmaUtil<19%, VALUBusy<40%, Occ<37%).
// Entry (8 x f16 = 16B): A: (ax,ay,az,1,0..0)  B: (-2bx,-2by,-2bz,|b|^2,0..0)
// 16x16x32 operand layout: lane l reads ent[l&15]; the 4 k-groups (l>>4) all
// read the SAME entry -> each product appears 4x -> result = 4x target,
// folded by *0.25f (exact). C/D layout (m89): col=lane&15,
// row=(lane>>4)*4+reg. Min over cols = shfl_xor 1,2,4,8 (stays in quarter).
// Per block (256 thr, 4 waves): 256 A-points (64/wave, 4 frags), B-slice
// 1024 staged once in LDS (16KB, single barrier), 64 B-frags.
__global__ __launch_bounds__(256, 4) void k_nn_all(
    const float* __restrict__ pc10, const float* __restrict__ pc11,
    const float* __restrict__ pc2, const float* __restrict__ pc3,
    float* __restrict__ ws) {
  const int tid = threadIdx.x;
  const int blk = blockIdx.x;
  __shared__ uint4 smem4[1344];  // 21504 B

  if (blk >= 2560) {  // confidence job: per-batch NN pc3[b] -> pc2[b], f32
    float4* tile4 = (float4*)smem4;
    int j = blk - 2560;
    if (j == 0 && tid < 9) ws[55296 + tid] = 0.f;  // zero acc[8] + ticket
    int b = j >> 3;
    int s = j & 7;
    int bi = b * 2048 + s * 256 + tid;
    {
      float bx = pc2[bi * 3 + 0], by = pc2[bi * 3 + 1], bz = pc2[bi * 3 + 2];
      tile4[tid] = make_float4(-2.f * bx, -2.f * by, -2.f * bz,
                               bx * bx + by * by + bz * bz);
    }
    int i = b * 256 + tid;
    float ax = pc3[i * 3 + 0], ay = pc3[i * 3 + 1], az = pc3[i * 3 + 2];
    float ra = ax * ax + ay * ay + az * az;
    __syncthreads();
    float mn = 3.0e38f;
#pragma unroll 4
    for (int t = 0; t < 256; ++t) {
      float4 q = tile4[t];
      float v = fmaf(q.x, ax, fmaf(q.y, ay, fmaf(q.z, az, q.w)));
      mn = fminf(mn, v);
    }
    atomicMin((unsigned int*)(ws + 53248 + i), __float_as_uint(fmaxf(mn + ra, 0.f)));
    return;
  }

  const float* A;
  const float* B;
  float* outMin;
  int aBase, bBase;
  if (blk < 1024) {           // job1: pc1_0 (16384) -> pc2 (16384)
    A = pc10; B = pc2; outMin = ws + 0;
    aBase = (blk >> 4) * 256; bBase = (blk & 15) * 1024;
  } else if (blk < 2048) {    // job2: pc2 (16384) -> pc1_0 (16384)
    int j = blk - 1024;
    A = pc2; B = pc10; outMin = ws + 16384;
    aBase = (j >> 4) * 256; bBase = (j & 15) * 1024;
  } else if (blk < 2304) {    // job3: pc1_1 (4096) -> pc2 (16384)
    int j = blk - 2048;
    A = pc11; B = pc2; outMin = ws + 32768;
    aBase = (j >> 4) * 256; bBase = (j & 15) * 1024;
  } else {                    // job4: pc2 (16384) -> pc1_1 (4096)
    int j = blk - 2304;
    A = pc2; B = pc11; outMin = ws + 36864;
    aBase = (j >> 2) * 256; bBase = (j & 3) * 1024;
  }

  half8* bEnt = (half8*)smem4;            // 1024 entries, 16 KB
  half8* aEnt = (half8*)(smem4 + 1024);   // 256 entries, 4 KB
  float* aRa  = (float*)(smem4 + 1280);   // 256 f32, 1 KB

  // A entries (one per thread)
  {
    int ai = aBase + tid;
    float x = A[ai * 3 + 0], y = A[ai * 3 + 1], z = A[ai * 3 + 2];
    half8 e = {};
    e[0] = (_Float16)x; e[1] = (_Float16)y; e[2] = (_Float16)z;
    e[3] = (_Float16)1.f;
    aEnt[tid] = e;
    aRa[tid] = fmaf(x, x, fmaf(y, y, z * z));
  }
  // stage 1024-point B slice (4 entries/thread)
#pragma unroll
  for (int e = tid; e < 1024; e += 256) {
    int bi = bBase + e;
    float x = B[bi * 3 + 0], y = B[bi * 3 + 1], z = B[bi * 3 + 2];
    half8 be = {};
    be[0] = (_Float16)(-2.f * x); be[1] = (_Float16)(-2.f * y);
    be[2] = (_Float16)(-2.f * z);
    be[3] = (_Float16)(fmaf(x, x, fmaf(y, y, z * z)));
    bEnt[e] = be;
  }
  __syncthreads();

  const int l = tid & 63;
  const int wid = tid >> 6;
  const int cl = l & 15;
  half8 a0 = aEnt[wid * 64 + cl];
  half8 a1 = aEnt[wid * 64 + 16 + cl];
  half8 a2 = aEnt[wid * 64 + 32 + cl];
  half8 a3 = aEnt[wid * 64 + 48 + cl];

  f32x4 m0, m1, m2, m3, zc;
#pragma unroll
  for (int r = 0; r < 4; ++r) {
    m0[r] = 3.0e38f; m1[r] = 3.0e38f; m2[r] = 3.0e38f; m3[r] = 3.0e38f;
    zc[r] = 0.f;
  }

  for (int bt = 0; bt < 64; bt += 2) {
    half8 b0 = bEnt[bt * 16 + cl];
    half8 b1 = bEnt[bt * 16 + 16 + cl];
    f32x4 c00 = __builtin_amdgcn_mfma_f32_16x16x32_f16(a0, b0, zc, 0, 0, 0);
    f32x4 c01 = __builtin_amdgcn_mfma_f32_16x16x32_f16(a0, b1, zc, 0, 0, 0);
    f32x4 c10 = __builtin_amdgcn_mfma_f32_16x16x32_f16(a1, b0, zc, 0, 0, 0);
    f32x4 c11 = __builtin_amdgcn_mfma_f32_16x16x32_f16(a1, b1, zc, 0, 0, 0);
    f32x4 c20 = __builtin_amdgcn_mfma_f32_16x16x32_f16(a2, b0, zc, 0, 0, 0);
    f32x4 c21 = __builtin_amdgcn_mfma_f32_16x16x32_f16(a2, b1, zc, 0, 0, 0);
    f32x4 c30 = __builtin_amdgcn_mfma_f32_16x16x32_f16(a3, b0, zc, 0, 0, 0);
    f32x4 c31 = __builtin_amdgcn_mfma_f32_16x16x32_f16(a3, b1, zc, 0, 0, 0);
#pragma unroll
    for (int r = 0; r < 4; ++r) {
      m0[r] = fminf(fminf(m0[r], c00[r]), c01[r]);  // -> v_min3_f32
      m1[r] = fminf(fminf(m1[r], c10[r]), c11[r]);
      m2[r] = fminf(fminf(m2[r], c20[r]), c21[r]);
      m3[r] = fminf(fminf(m3[r], c30[r]), c31[r]);
    }
  }

  // min over the 16 cols (within each 16-lane quarter; xor<16 stays inside)
#pragma unroll
  for (int r = 0; r < 4; ++r) {
    float v0 = m0[r], v1 = m1[r], v2 = m2[r], v3 = m3[r];
    v0 = fminf(v0, __shfl_xor(v0, 1));
    v1 = fminf(v1, __shfl_xor(v1, 1));
    v2 = fminf(v2, __shfl_xor(v2, 1));
    v3 = fminf(v3, __shfl_xor(v3, 1));
    v0 = fminf(v0, __shfl_xor(v0, 2));
    v1 = fminf(v1, __shfl_xor(v1, 2));
    v2 = fminf(v2, __shfl_xor(v2, 2));
    v3 = fminf(v3, __shfl_xor(v3, 2));
    v0 = fminf(v0, __shfl_xor(v0, 4));
    v1 = fminf(v1, __shfl_xor(v1, 4));
    v2 = fminf(v2, __shfl_xor(v2, 4));
    v3 = fminf(v3, __shfl_xor(v3, 4));
    v0 = fminf(v0, __shfl_xor(v0, 8));
    v1 = fminf(v1, __shfl_xor(v1, 8));
    v2 = fminf(v2, __shfl_xor(v2, 8));
    v3 = fminf(v3, __shfl_xor(v3, 8));
    m0[r] = v0; m1[r] = v1; m2[r] = v2; m3[r] = v3;
  }
  if (cl == 0) {
    int qg = l >> 4;  // quarter index: rows qg*4 .. qg*4+3
#pragma unroll
    for (int r = 0; r < 4; ++r) {
      int row = qg * 4 + r;
      int base = aBase + wid * 64;
      atomicMin((unsigned int*)(outMin + base + row),
                __float_as_uint(fmaxf(fmaf(0.25f, m0[r], aRa[wid * 64 + row]), 0.f)));
      atomicMin((unsigned int*)(outMin + base + 16 + row),
                __float_as_uint(fmaxf(fmaf(0.25f, m1[r], aRa[wid * 64 + 16 + row]), 0.f)));
      atomicMin((unsigned int*)(outMin + base + 32 + row),
                __float_as_uint(fmaxf(fmaf(0.25f, m2[r], aRa[wid * 64 + 32 + row]), 0.f)));
      atomicMin((unsigned int*)(outMin + base + 48 + row),
                __float_as_uint(fmaxf(fmaf(0.25f, m3[r], aRa[wid * 64 + 48 + row]), 0.f)));
    }
  }
}

// Segmented reduce + final combine (ticket: last block writes out).
__global__ __launch_bounds__(256) void k_reduce(
    const float* __restrict__ ws, const float* __restrict__ pc13,
    const float* __restrict__ pc10, const float* __restrict__ pc2,
    float* __restrict__ acc, unsigned int* __restrict__ ticket,
    float* __restrict__ out) {
  __shared__ float sbuf[4];
  int idx = blockIdx.x * 256 + threadIdx.x;
  float v;
  int k;
  if (idx < 53248) {
    v = sqrtf(fmaxf(ws[idx], 0.f));
    k = (idx < 16384) ? 0 : (idx < 32768) ? 1 : (idx < 36864) ? 2 : 3;
  } else if (idx < 55296) {
    int i = idx - 53248;
    float score = expf(-sqrtf(fmaxf(ws[idx], 0.f)));
    float d = pc13[i] - score;
    v = d * d;
    k = 4;
  } else {
    int i = idx - 55296;
    float d = pc10[i] - pc2[i];
    v = d * d;
    k = 5;
  }
  float s = blockReduceSum(v, sbuf);
  if (threadIdx.x == 0) {
    atomicAdd(acc + k, s);
    __threadfence();
    unsigned int t = atomicAdd(ticket, 1u);
    if (t == gridDim.x - 1) {
      __threadfence();
      float cd   = (acc[0] + acc[1]) * (1.f / 16384.f);
      float seed = acc[2] * (1.f / 4096.f) + acc[3] * (1.f / 16384.f);
      float conf = acc[4] * (1.f / 2048.f);
      float p2p  = acc[5] * (1.f / 49152.f);
      out[0] = 0.5f * cd + 0.5f * seed + 0.5f * conf + p2p;
    }
  }
}

extern "C" void kernel_launch(void* const* d_in, const int* in_sizes, int n_in,
                              void* d_out, int out_size, void* d_ws, size_t ws_size,
                              hipStream_t stream) {
  const float* pc10 = (const float*)d_in[0];
  const float* pc11 = (const float*)d_in[1];
  const float* pc13 = (const float*)d_in[2];
  const float* pc2  = (const float*)d_in[3];
  const float* pc3  = (const float*)d_in[4];
  float* ws  = (float*)d_ws;
  float* acc = ws + N_MINS;
  float* out = (float*)d_out;

  // init: min arrays to ~3.39e38 (0x7F7F7F7F); acc/ticket zeroed in k_nn_all
  (void)hipMemsetAsync(ws, 0x7F, N_MINS * sizeof(float), stream);

  k_nn_all<<<2624, 256, 0, stream>>>(pc10, pc11, pc2, pc3, ws);

  int reduce_blocks = (N_MINS + 49152) / 256;  // 408
  k_reduce<<<reduce_blocks, 256, 0, stream>>>(ws, pc13, pc10, pc2, acc,
                                              (unsigned int*)(ws + 55304), out);
}

// Round 23
// 55.903 us; speedup vs baseline: 1.1250x; 1.1250x over previous
//
#include <hip/hip_runtime.h>
#include <hip/hip_fp16.h>

// Sizes (fixed):
// pc1_0: [8,2048,3] -> 16384 pts   d_in[0]
// pc1_1: [8, 512,3] ->  4096 pts   d_in[1]
// pc1_3: [8, 256,1] ->  2048 vals  d_in[2]
// pc2  : [8,2048,3] -> 16384 pts   d_in[3]
// pc3  : [8, 256,3] ->  2048 pts   d_in[4]
//
// ws layout (floats):
//   [0      ,16384) minA0 : pc1_0 -> pc2   (cd, a->b)
//   [16384  ,32768) minB0 : pc2   -> pc1_0 (cd, b->a)
//   [32768  ,36864) minA1 : pc1_1 -> pc2   (seed, a->b)
//   [36864  ,53248) minB1 : pc2   -> pc1_1 (seed, b->a)
//   [53248  ,55296) minC  : pc3[b] -> pc2[b] (confidence, full f32)
//   [55296  ,55304) acc[8]
//   [55304]         ticket

#define N_MINS 55296

typedef _Float16 half8 __attribute__((ext_vector_type(8)));
typedef float f32x16 __attribute__((ext_vector_type(16)));

__device__ __forceinline__ float blockReduceSum(float v, float* sbuf) {
#pragma unroll
  for (int off = 32; off > 0; off >>= 1) v += __shfl_down(v, off, 64);
  int lane = threadIdx.x & 63;
  int wid  = threadIdx.x >> 6;
  if (lane == 0) sbuf[wid] = v;
  __syncthreads();
  float r = 0.f;
  if (threadIdx.x == 0) r = sbuf[0] + sbuf[1] + sbuf[2] + sbuf[3];
  return r;
}

// MFMA NN-min kernel: 32x32x16 (best pair-efficiency: 127 pairs/cyc/CU at 2x
// k-dup), NO software pipeline (R18's pipeline added 64+ regs of state and
// cut occupancy to 3 waves/SIMD -- latency was never hidden). One B-tile in
// flight; TLP from >=4 waves/SIMD ((256,4): <=128 unified regs) hides MFMA
// and LDS latency instead.
// Entry (8 x f16 = 16B): A: (ax,ay,az,1,0..0)  B: (-2bx,-2by,-2bz,|b|^2,0..0)
// One v_mfma_f32_32x32x16_f16 => 32x32 tile of (|b|^2 - 2 a.b), f32 acc.
// Entries duplicated into both k-halves => result is 2x target; folded by
// final *0.5f. C/D layout (verified R13-R18, absmax 0): col=lane&31,
// row=(reg&3)+8*(reg>>2)+4*(lane>>5).
// Per block (256 thr, 4 waves): 256 A-points (2 frags/wave), B-slice 2048 in
// 2 LDS chunks of 1024.
__global__ __launch_bounds__(256, 4) void k_nn_all(
    const float* __restrict__ pc10, const float* __restrict__ pc11,
    const float* __restrict__ pc2, const float* __restrict__ pc3,
    float* __restrict__ ws) {
  const int tid = threadIdx.x;
  const int blk = blockIdx.x;
  __shared__ uint4 smem4[1344];  // 21504 B

  if (blk >= 1280) {  // confidence job: per-batch NN pc3[b] -> pc2[b], f32
    float4* tile4 = (float4*)smem4;
    int j = blk - 1280;
    if (j == 0 && tid < 9) ws[55296 + tid] = 0.f;  // zero acc[8] + ticket
    int b = j >> 3;
    int s = j & 7;
    int bi = b * 2048 + s * 256 + tid;
    {
      float bx = pc2[bi * 3 + 0], by = pc2[bi * 3 + 1], bz = pc2[bi * 3 + 2];
      tile4[tid] = make_float4(-2.f * bx, -2.f * by, -2.f * bz,
                               bx * bx + by * by + bz * bz);
    }
    int i = b * 256 + tid;
    float ax = pc3[i * 3 + 0], ay = pc3[i * 3 + 1], az = pc3[i * 3 + 2];
    float ra = ax * ax + ay * ay + az * az;
    __syncthreads();
    float mn = 3.0e38f;
#pragma unroll 4
    for (int t = 0; t < 256; ++t) {
      float4 q = tile4[t];
      float v = fmaf(q.x, ax, fmaf(q.y, ay, fmaf(q.z, az, q.w)));
      mn = fminf(mn, v);
    }
    atomicMin((unsigned int*)(ws + 53248 + i), __float_as_uint(fmaxf(mn + ra, 0.f)));
    return;
  }

  const float* A;
  const float* B;
  float* outMin;
  int aBase, bBase;
  if (blk < 512) {            // job1: pc1_0 (16384) -> pc2 (16384)
    A = pc10; B = pc2; outMin = ws + 0;
    aBase = (blk >> 3) * 256; bBase = (blk & 7) * 2048;
  } else if (blk < 1024) {    // job2: pc2 (16384) -> pc1_0 (16384)
    int j = blk - 512;
    A = pc2; B = pc10; outMin = ws + 16384;
    aBase = (j >> 3) * 256; bBase = (j & 7) * 2048;
  } else if (blk < 1152) {    // job3: pc1_1 (4096) -> pc2 (16384)
    int j = blk - 1024;
    A = pc11; B = pc2; outMin = ws + 32768;
    aBase = (j >> 3) * 256; bBase = (j & 7) * 2048;
  } else {                    // job4: pc2 (16384) -> pc1_1 (4096)
    int j = blk - 1152;
    A = pc2; B = pc11; outMin = ws + 36864;
    aBase = (j >> 1) * 256; bBase = (j & 1) * 2048;
  }

  half8* bEnt = (half8*)smem4;            // 1024 entries, 16 KB
  half8* aEnt = (half8*)(smem4 + 1024);   // 256 entries, 4 KB
  float* aRa  = (float*)(smem4 + 1280);   // 256 f32, 1 KB

  // A entries (one per thread)
  {
    int ai = aBase + tid;
    float x = A[ai * 3 + 0], y = A[ai * 3 + 1], z = A[ai * 3 + 2];
    half8 e = {};
    e[0] = (_Float16)x; e[1] = (_Float16)y; e[2] = (_Float16)z;
    e[3] = (_Float16)1.f;
    aEnt[tid] = e;
    aRa[tid] = fmaf(x, x, fmaf(y, y, z * z));
  }
  // stage B chunk 0
#pragma unroll
  for (int e = tid; e < 1024; e += 256) {
    int bi = bBase + e;
    float x = B[bi * 3 + 0], y = B[bi * 3 + 1], z = B[bi * 3 + 2];
    half8 be = {};
    be[0] = (_Float16)(-2.f * x); be[1] = (_Float16)(-2.f * y);
    be[2] = (_Float16)(-2.f * z);
    be[3] = (_Float16)(fmaf(x, x, fmaf(y, y, z * z)));
    bEnt[e] = be;
  }
  __syncthreads();

  const int l = tid & 63;
  const int wid = tid >> 6;
  const int col = l & 31;
  half8 a80 = aEnt[wid * 64 + col];
  half8 a81 = aEnt[wid * 64 + 32 + col];

  f32x16 mn0, mn1, zc;
#pragma unroll
  for (int r = 0; r < 16; ++r) { mn0[r] = 3.0e38f; mn1[r] = 3.0e38f; zc[r] = 0.f; }

  for (int c = 0; c < 2; ++c) {
    if (c) {
      __syncthreads();
#pragma unroll
      for (int e = tid; e < 1024; e += 256) {
        int bi = bBase + 1024 + e;
        float x = B[bi * 3 + 0], y = B[bi * 3 + 1], z = B[bi * 3 + 2];
        half8 be = {};
        be[0] = (_Float16)(-2.f * x); be[1] = (_Float16)(-2.f * y);
        be[2] = (_Float16)(-2.f * z);
        be[3] = (_Float16)(fmaf(x, x, fmaf(y, y, z * z)));
        bEnt[e] = be;
      }
      __syncthreads();
    }
    for (int bt = 0; bt < 32; ++bt) {
      half8 b = bEnt[bt * 32 + col];
      f32x16 c0 = __builtin_amdgcn_mfma_f32_32x32x16_f16(a80, b, zc, 0, 0, 0);
#pragma unroll
      for (int r = 0; r < 16; ++r)
        mn0[r] = fminf(mn0[r], c0[r]);
      f32x16 c1 = __builtin_amdgcn_mfma_f32_32x32x16_f16(a81, b, zc, 0, 0, 0);
#pragma unroll
      for (int r = 0; r < 16; ++r)
        mn1[r] = fminf(mn1[r], c1[r]);
    }
  }

  // min over the 32 cols (within each 32-lane half), then write 64 rows/wave
#pragma unroll
  for (int r = 0; r < 16; ++r) {
    float v0 = mn0[r], v1 = mn1[r];
    v0 = fminf(v0, __shfl_xor(v0, 1));
    v1 = fminf(v1, __shfl_xor(v1, 1));
    v0 = fminf(v0, __shfl_xor(v0, 2));
    v1 = fminf(v1, __shfl_xor(v1, 2));
    v0 = fminf(v0, __shfl_xor(v0, 4));
    v1 = fminf(v1, __shfl_xor(v1, 4));
    v0 = fminf(v0, __shfl_xor(v0, 8));
    v1 = fminf(v1, __shfl_xor(v1, 8));
    v0 = fminf(v0, __shfl_xor(v0, 16));
    v1 = fminf(v1, __shfl_xor(v1, 16));
    mn0[r] = v0;
    mn1[r] = v1;
  }
  if (col == 0) {
    int hi = l >> 5;
#pragma unroll
    for (int r = 0; r < 16; ++r) {
      int row = (r & 3) + 8 * (r >> 2) + 4 * hi;
      int a0 = aBase + wid * 64 + row;
      int a1 = a0 + 32;
      atomicMin((unsigned int*)(outMin + a0),
                __float_as_uint(fmaxf(fmaf(0.5f, mn0[r], aRa[wid * 64 + row]), 0.f)));
      atomicMin((unsigned int*)(outMin + a1),
                __float_as_uint(fmaxf(fmaf(0.5f, mn1[r], aRa[wid * 64 + 32 + row]), 0.f)));
    }
  }
}

// Segmented reduce + final combine (ticket: last block writes out).
__global__ __launch_bounds__(256) void k_reduce(
    const float* __restrict__ ws, const float* __restrict__ pc13,
    const float* __restrict__ pc10, const float* __restrict__ pc2,
    float* __restrict__ acc, unsigned int* __restrict__ ticket,
    float* __restrict__ out) {
  __shared__ float sbuf[4];
  int idx = blockIdx.x * 256 + threadIdx.x;
  float v;
  int k;
  if (idx < 53248) {
    v = sqrtf(fmaxf(ws[idx], 0.f));
    k = (idx < 16384) ? 0 : (idx < 32768) ? 1 : (idx < 36864) ? 2 : 3;
  } else if (idx < 55296) {
    int i = idx - 53248;
    float score = expf(-sqrtf(fmaxf(ws[idx], 0.f)));
    float d = pc13[i] - score;
    v = d * d;
    k = 4;
  } else {
    int i = idx - 55296;
    float d = pc10[i] - pc2[i];
    v = d * d;
    k = 5;
  }
  float s = blockReduceSum(v, sbuf);
  if (threadIdx.x == 0) {
    atomicAdd(acc + k, s);
    __threadfence();
    unsigned int t = atomicAdd(ticket, 1u);
    if (t == gridDim.x - 1) {
      __threadfence();
      float cd   = (acc[0] + acc[1]) * (1.f / 16384.f);
      float seed = acc[2] * (1.f / 4096.f) + acc[3] * (1.f / 16384.f);
      float conf = acc[4] * (1.f / 2048.f);
      float p2p  = acc[5] * (1.f / 49152.f);
      out[0] = 0.5f * cd + 0.5f * seed + 0.5f * conf + p2p;
    }
  }
}

extern "C" void kernel_launch(void* const* d_in, const int* in_sizes, int n_in,
                              void* d_out, int out_size, void* d_ws, size_t ws_size,
                              hipStream_t stream) {
  const float* pc10 = (const float*)d_in[0];
  const float* pc11 = (const float*)d_in[1];
  const float* pc13 = (const float*)d_in[2];
  const float* pc2  = (const float*)d_in[3];
  const float* pc3  = (const float*)d_in[4];
  float* ws  = (float*)d_ws;
  float* acc = ws + N_MINS;
  float* out = (float*)d_out;

  // init: min arrays to ~3.39e38 (0x7F7F7F7F); acc/ticket zeroed in k_nn_all
  (void)hipMemsetAsync(ws, 0x7F, N_MINS * sizeof(float), stream);

  k_nn_all<<<1344, 256, 0, stream>>>(pc10, pc11, pc2, pc3, ws);

  int reduce_blocks = (N_MINS + 49152) / 256;  // 408
  k_reduce<<<reduce_blocks, 256, 0, stream>>>(ws, pc13, pc10, pc2, acc,
                                              (unsigned int*)(ws + 55304), out);
}